// Round 1
// baseline (1127.198 us; speedup 1.0000x reference)
//
#include <hip/hip_runtime.h>
#include <math.h>

#define BB 16
#define TT 4096
#define HH 768
#define DD 64
#define MM 256
#define BT (BB*TT)

__device__ __forceinline__ void fma4(float& acc, float4 a, float4 b){
    acc = __builtin_fmaf(a.x, b.x, acc);
    acc = __builtin_fmaf(a.y, b.y, acc);
    acc = __builtin_fmaf(a.z, b.z, acc);
    acc = __builtin_fmaf(a.w, b.w, acc);
}

// K1: q/k/v = x @ [Wq|Wk|Wv] + bias.  64 rows/block, KC=32, N=192.
__global__ __launch_bounds__(256) void qkv_kernel(
    const float* __restrict__ x,
    const float* __restrict__ Wq, const float* __restrict__ bq,
    const float* __restrict__ Wk, const float* __restrict__ bk,
    const float* __restrict__ Wv, const float* __restrict__ bv,
    float* __restrict__ q, float* __restrict__ k, float* __restrict__ v)
{
    __shared__ float xs[64][36];    // 64 rows x 32 k (pad->36, 16B aligned)
    __shared__ float ws[32][196];   // 32 k x 192 cols (q|k|v), pad->196
    const int tid = threadIdx.x;
    const int row0 = blockIdx.x * 64;
    const int tr = tid >> 4, tc = tid & 15;

    float4 acc[4][3];
    #pragma unroll
    for (int r = 0; r < 4; r++)
        #pragma unroll
        for (int c = 0; c < 3; c++) acc[r][c] = make_float4(0.f,0.f,0.f,0.f);

    for (int kc = 0; kc < HH; kc += 32){
        __syncthreads();
        // stage x tile: 64x32 floats
        #pragma unroll
        for (int i = 0; i < 2; i++){
            int l = tid + i*256;
            int r = l >> 3, j4 = (l & 7) << 2;
            *(float4*)&xs[r][j4] = *(const float4*)&x[(size_t)(row0+r)*HH + kc + j4];
        }
        // stage W tile: 32 x (64|64|64)
        #pragma unroll
        for (int i = 0; i < 2; i++){
            int l = tid + i*256;
            int kk = l >> 4, c4 = (l & 15) << 2;
            *(float4*)&ws[kk][c4]       = *(const float4*)&Wq[(size_t)(kc+kk)*DD + c4];
            *(float4*)&ws[kk][64 + c4]  = *(const float4*)&Wk[(size_t)(kc+kk)*DD + c4];
            *(float4*)&ws[kk][128 + c4] = *(const float4*)&Wv[(size_t)(kc+kk)*DD + c4];
        }
        __syncthreads();
        #pragma unroll
        for (int kk = 0; kk < 32; kk++){
            float xv[4];
            float4 wv[3];
            #pragma unroll
            for (int r = 0; r < 4; r++) xv[r] = xs[tr*4+r][kk];
            #pragma unroll
            for (int c = 0; c < 3; c++) wv[c] = *(float4*)&ws[kk][tc*12 + c*4];
            #pragma unroll
            for (int r = 0; r < 4; r++)
                #pragma unroll
                for (int c = 0; c < 3; c++){
                    acc[r][c].x = __builtin_fmaf(xv[r], wv[c].x, acc[r][c].x);
                    acc[r][c].y = __builtin_fmaf(xv[r], wv[c].y, acc[r][c].y);
                    acc[r][c].z = __builtin_fmaf(xv[r], wv[c].z, acc[r][c].z);
                    acc[r][c].w = __builtin_fmaf(xv[r], wv[c].w, acc[r][c].w);
                }
        }
    }
    // epilogue: bias + split write.  Each float4 group of 4 cols lies in one matrix.
    #pragma unroll
    for (int c = 0; c < 3; c++){
        int col = tc*12 + c*4;
        int sel = col >> 6;
        int d = col & 63;
        const float* bias = (sel==0) ? bq : (sel==1) ? bk : bv;
        float* dst = (sel==0) ? q : (sel==1) ? k : v;
        float4 b4 = *(const float4*)&bias[d];
        #pragma unroll
        for (int r = 0; r < 4; r++){
            size_t grow = (size_t)(row0 + tr*4 + r);
            float4 o;
            o.x = acc[r][c].x + b4.x;
            o.y = acc[r][c].y + b4.y;
            o.z = acc[r][c].z + b4.z;
            o.w = acc[r][c].w + b4.w;
            *(float4*)&dst[grow*DD + d] = o;
        }
    }
}

// K2: kp = exp(k @ w^T - 0.5||k||^2) / 16.  64 rows/block, m chunked by 64.
__global__ __launch_bounds__(256) void kp_kernel(
    const float* __restrict__ k, const float* __restrict__ w, float* __restrict__ kp)
{
    __shared__ float ks_[64][68];
    __shared__ float ws_[64][68];
    __shared__ float xd_s[64];
    const int tid = threadIdx.x;
    const int row0 = blockIdx.x * 64;
    const int tr = tid >> 4, tc = tid & 15;

    #pragma unroll
    for (int i = 0; i < 4; i++){
        int l = tid + i*256;
        int r = l >> 4, c4 = (l & 15) << 2;
        *(float4*)&ks_[r][c4] = *(const float4*)&k[(size_t)(row0+r)*DD + c4];
    }
    __syncthreads();
    {   // row norms: 4 threads/row, 16 d each, shfl reduce
        int rowx = tid >> 2, sub = tid & 3;
        float s = 0.f;
        #pragma unroll
        for (int j = 0; j < 4; j++){
            float4 kv = *(float4*)&ks_[rowx][sub*16 + j*4];
            s += kv.x*kv.x + kv.y*kv.y + kv.z*kv.z + kv.w*kv.w;
        }
        s += __shfl_xor(s, 1);
        s += __shfl_xor(s, 2);
        if (sub == 0) xd_s[rowx] = 0.5f * s;
    }

    for (int mc = 0; mc < 4; mc++){
        __syncthreads();
        #pragma unroll
        for (int i = 0; i < 4; i++){
            int l = tid + i*256;
            int r = l >> 4, c4 = (l & 15) << 2;
            *(float4*)&ws_[r][c4] = *(const float4*)&w[(size_t)(mc*64 + r)*DD + c4];
        }
        __syncthreads();
        float acc[4][4];
        #pragma unroll
        for (int r = 0; r < 4; r++)
            #pragma unroll
            for (int c = 0; c < 4; c++) acc[r][c] = 0.f;
        #pragma unroll
        for (int d4 = 0; d4 < 16; d4++){
            float4 qv[4], wv[4];
            #pragma unroll
            for (int r = 0; r < 4; r++) qv[r] = *(float4*)&ks_[tr*4+r][d4*4];
            #pragma unroll
            for (int c = 0; c < 4; c++) wv[c] = *(float4*)&ws_[tc + 16*c][d4*4];
            #pragma unroll
            for (int r = 0; r < 4; r++)
                #pragma unroll
                for (int c = 0; c < 4; c++) fma4(acc[r][c], qv[r], wv[c]);
        }
        #pragma unroll
        for (int r = 0; r < 4; r++){
            float xd = xd_s[tr*4+r];
            #pragma unroll
            for (int c = 0; c < 4; c++){
                float val = expf(acc[r][c] - xd) * 0.0625f;
                kp[(size_t)(row0 + tr*4 + r)*MM + mc*64 + tc + 16*c] = val;
            }
        }
    }
}

// K3: kptv[b,n,m] += v^T @ kp (T-split x16 per batch, fp32 atomics); ksum[b,m] too.
__global__ __launch_bounds__(256) void kptv_kernel(
    const float* __restrict__ v, const float* __restrict__ kp,
    float* __restrict__ out_kptv, float* __restrict__ ksum)
{
    __shared__ float vs[32][68];
    __shared__ float kps[32][260];
    const int tid = threadIdx.x;
    const int b = blockIdx.y;
    const int t0 = blockIdx.x * 256;
    const int tn = tid >> 4, tm = tid & 15;
    float acc[4][16];
    #pragma unroll
    for (int r = 0; r < 4; r++)
        #pragma unroll
        for (int c = 0; c < 16; c++) acc[r][c] = 0.f;
    float ks[16];
    #pragma unroll
    for (int c = 0; c < 16; c++) ks[c] = 0.f;

    for (int tt = 0; tt < 256; tt += 32){
        __syncthreads();
        #pragma unroll
        for (int i = 0; i < 2; i++){
            int l = tid + i*256;
            int r = l >> 4, c4 = (l & 15) << 2;
            *(float4*)&vs[r][c4] = *(const float4*)&v[(size_t)(b*TT + t0 + tt + r)*DD + c4];
        }
        #pragma unroll
        for (int i = 0; i < 8; i++){
            int l = tid + i*256;
            int r = l >> 6, c4 = (l & 63) << 2;
            *(float4*)&kps[r][c4] = *(const float4*)&kp[(size_t)(b*TT + t0 + tt + r)*MM + c4];
        }
        __syncthreads();
        #pragma unroll
        for (int t = 0; t < 32; t++){
            float vv[4], kv[16];
            #pragma unroll
            for (int r = 0; r < 4; r++) vv[r] = vs[t][tn*4 + r];
            #pragma unroll
            for (int c = 0; c < 16; c++) kv[c] = kps[t][tm + 16*c];
            #pragma unroll
            for (int r = 0; r < 4; r++)
                #pragma unroll
                for (int c = 0; c < 16; c++)
                    acc[r][c] = __builtin_fmaf(vv[r], kv[c], acc[r][c]);
            if (tn == 0){
                #pragma unroll
                for (int c = 0; c < 16; c++) ks[c] += kv[c];
            }
        }
    }
    #pragma unroll
    for (int r = 0; r < 4; r++)
        #pragma unroll
        for (int c = 0; c < 16; c++)
            unsafeAtomicAdd(&out_kptv[(size_t)b*DD*MM + (tn*4 + r)*MM + tm + 16*c], acc[r][c]);
    if (tn == 0){
        #pragma unroll
        for (int c = 0; c < 16; c++)
            unsafeAtomicAdd(&ksum[b*MM + tm + 16*c], ks[c]);
    }
}

// K4: qp = prm_exp(q) recomputed on the fly; attn = (qp @ kptv^T) / (qp . ksum).
__global__ __launch_bounds__(256) void attn_kernel(
    const float* __restrict__ q, const float* __restrict__ w,
    const float* __restrict__ kptv, const float* __restrict__ ksum,
    float* __restrict__ out)
{
    __shared__ float qs[64][68];
    __shared__ float wqp[64][68];   // holds w chunk during GEMM1, qp tile during GEMM2
    __shared__ float kvs[64][68];   // kptv chunk [n][m-chunk]
    __shared__ float ksum_s[256];
    __shared__ float xd_s[64];
    const int tid = threadIdx.x;
    const int row0 = blockIdx.x * 64;
    const int b = row0 >> 12;       // /4096
    const int tr = tid >> 4, tc = tid & 15;

    #pragma unroll
    for (int i = 0; i < 4; i++){
        int l = tid + i*256;
        int r = l >> 4, c4 = (l & 15) << 2;
        *(float4*)&qs[r][c4] = *(const float4*)&q[(size_t)(row0 + r)*DD + c4];
    }
    ksum_s[tid] = ksum[b*MM + tid];
    __syncthreads();
    {
        int rowx = tid >> 2, sub = tid & 3;
        float s = 0.f;
        #pragma unroll
        for (int j = 0; j < 4; j++){
            float4 qv = *(float4*)&qs[rowx][sub*16 + j*4];
            s += qv.x*qv.x + qv.y*qv.y + qv.z*qv.z + qv.w*qv.w;
        }
        s += __shfl_xor(s, 1);
        s += __shfl_xor(s, 2);
        if (sub == 0) xd_s[rowx] = 0.5f * s;
    }

    float acc2[4][4];
    float dn[4];
    #pragma unroll
    for (int r = 0; r < 4; r++){
        dn[r] = 0.f;
        #pragma unroll
        for (int c = 0; c < 4; c++) acc2[r][c] = 0.f;
    }

    for (int mc = 0; mc < 4; mc++){
        __syncthreads();   // prev GEMM2 readers done; xd_s visible on first iter
        #pragma unroll
        for (int i = 0; i < 4; i++){
            int l = tid + i*256;
            int r = l >> 4, c4 = (l & 15) << 2;
            *(float4*)&wqp[r][c4] = *(const float4*)&w[(size_t)(mc*64 + r)*DD + c4];
            *(float4*)&kvs[r][c4] = *(const float4*)&kptv[(size_t)b*DD*MM + r*MM + mc*64 + c4];
        }
        __syncthreads();
        // GEMM1: wtx for m-chunk
        float acc1[4][4];
        #pragma unroll
        for (int r = 0; r < 4; r++)
            #pragma unroll
            for (int c = 0; c < 4; c++) acc1[r][c] = 0.f;
        #pragma unroll
        for (int d4 = 0; d4 < 16; d4++){
            float4 qv[4], wv[4];
            #pragma unroll
            for (int r = 0; r < 4; r++) qv[r] = *(float4*)&qs[tr*4+r][d4*4];
            #pragma unroll
            for (int c = 0; c < 4; c++) wv[c] = *(float4*)&wqp[tc + 16*c][d4*4];
            #pragma unroll
            for (int r = 0; r < 4; r++)
                #pragma unroll
                for (int c = 0; c < 4; c++) fma4(acc1[r][c], qv[r], wv[c]);
        }
        // exp + Dn partials
        float qp_[4][4];
        #pragma unroll
        for (int r = 0; r < 4; r++){
            float xd = xd_s[tr*4+r];
            #pragma unroll
            for (int c = 0; c < 4; c++){
                float val = expf(acc1[r][c] - xd) * 0.0625f;
                qp_[r][c] = val;
                dn[r] = __builtin_fmaf(val, ksum_s[mc*64 + tc + 16*c], dn[r]);
            }
        }
        __syncthreads();   // everyone done reading w chunk
        #pragma unroll
        for (int r = 0; r < 4; r++)
            #pragma unroll
            for (int c = 0; c < 4; c++)
                wqp[tr*4+r][tc + 16*c] = qp_[r][c];
        __syncthreads();
        // GEMM2: acc2 += qp_tile @ kptv_chunk^T
        #pragma unroll
        for (int m4 = 0; m4 < 16; m4++){
            float4 qv[4], kv[4];
            #pragma unroll
            for (int r = 0; r < 4; r++) qv[r] = *(float4*)&wqp[tr*4+r][m4*4];
            #pragma unroll
            for (int c = 0; c < 4; c++) kv[c] = *(float4*)&kvs[tc + 16*c][m4*4];
            #pragma unroll
            for (int r = 0; r < 4; r++)
                #pragma unroll
                for (int c = 0; c < 4; c++) fma4(acc2[r][c], qv[r], kv[c]);
        }
    }
    #pragma unroll
    for (int r = 0; r < 4; r++){
        dn[r] += __shfl_xor(dn[r], 1);
        dn[r] += __shfl_xor(dn[r], 2);
        dn[r] += __shfl_xor(dn[r], 4);
        dn[r] += __shfl_xor(dn[r], 8);
    }
    #pragma unroll
    for (int r = 0; r < 4; r++){
        float inv = 1.0f / dn[r];
        #pragma unroll
        for (int c = 0; c < 4; c++)
            out[(size_t)(row0 + tr*4 + r)*DD + tc + 16*c] = acc2[r][c] * inv;
    }
}

extern "C" void kernel_launch(void* const* d_in, const int* in_sizes, int n_in,
                              void* d_out, int out_size, void* d_ws, size_t ws_size,
                              hipStream_t stream) {
    const float* x  = (const float*)d_in[0];
    const float* Wq = (const float*)d_in[1];
    const float* bq = (const float*)d_in[2];
    const float* Wk = (const float*)d_in[3];
    const float* bk = (const float*)d_in[4];
    const float* Wv = (const float*)d_in[5];
    const float* bv = (const float*)d_in[6];
    const float* w  = (const float*)d_in[7];

    float* out_attn = (float*)d_out;
    float* out_kptv = out_attn + (size_t)BB*TT*DD;

    float* q    = (float*)d_ws;                 // BT*64
    float* k    = q + (size_t)BT*DD;            // BT*64
    float* v    = k + (size_t)BT*DD;            // BT*64
    float* kp   = v + (size_t)BT*DD;            // BT*256
    float* ksum = kp + (size_t)BT*MM;           // B*256
    // total ws: ~112 MB

    hipMemsetAsync(out_kptv, 0, (size_t)BB*DD*MM*sizeof(float), stream);
    hipMemsetAsync(ksum, 0, (size_t)BB*MM*sizeof(float), stream);

    qkv_kernel<<<BT/64, 256, 0, stream>>>(x, Wq, bq, Wk, bk, Wv, bv, q, k, v);
    kp_kernel<<<BT/64, 256, 0, stream>>>(k, w, kp);
    kptv_kernel<<<dim3(16,16), 256, 0, stream>>>(v, kp, out_kptv, ksum);
    attn_kernel<<<BT/64, 256, 0, stream>>>(q, w, out_kptv, ksum, out_attn);
}

// Round 2
// 679.896 us; speedup vs baseline: 1.6579x; 1.6579x over previous
//
#include <hip/hip_runtime.h>
#include <math.h>

#define BB 16
#define TT 4096
#define HH 768
#define DD 64
#define MM 256
#define BT (BB*TT)
#define TSPLIT 16

__device__ __forceinline__ void fma4(float& acc, float4 a, float4 b){
    acc = __builtin_fmaf(a.x, b.x, acc);
    acc = __builtin_fmaf(a.y, b.y, acc);
    acc = __builtin_fmaf(a.z, b.z, acc);
    acc = __builtin_fmaf(a.w, b.w, acc);
}

// K1: q/k/v = x @ [Wq|Wk|Wv] + bias.  64 rows/block, KC=32, N=192.
__global__ __launch_bounds__(256) void qkv_kernel(
    const float* __restrict__ x,
    const float* __restrict__ Wq, const float* __restrict__ bq,
    const float* __restrict__ Wk, const float* __restrict__ bk,
    const float* __restrict__ Wv, const float* __restrict__ bv,
    float* __restrict__ q, float* __restrict__ k, float* __restrict__ v)
{
    __shared__ float xs[64][36];    // 64 rows x 32 k (pad->36, 16B aligned)
    __shared__ float ws[32][196];   // 32 k x 192 cols (q|k|v), pad->196
    const int tid = threadIdx.x;
    const int row0 = blockIdx.x * 64;
    const int tr = tid >> 4, tc = tid & 15;

    float4 acc[4][3];
    #pragma unroll
    for (int r = 0; r < 4; r++)
        #pragma unroll
        for (int c = 0; c < 3; c++) acc[r][c] = make_float4(0.f,0.f,0.f,0.f);

    for (int kc = 0; kc < HH; kc += 32){
        __syncthreads();
        // stage x tile: 64x32 floats
        #pragma unroll
        for (int i = 0; i < 2; i++){
            int l = tid + i*256;
            int r = l >> 3, j4 = (l & 7) << 2;
            *(float4*)&xs[r][j4] = *(const float4*)&x[(size_t)(row0+r)*HH + kc + j4];
        }
        // stage W tile: 32 x (64|64|64)
        #pragma unroll
        for (int i = 0; i < 2; i++){
            int l = tid + i*256;
            int kk = l >> 4, c4 = (l & 15) << 2;
            *(float4*)&ws[kk][c4]       = *(const float4*)&Wq[(size_t)(kc+kk)*DD + c4];
            *(float4*)&ws[kk][64 + c4]  = *(const float4*)&Wk[(size_t)(kc+kk)*DD + c4];
            *(float4*)&ws[kk][128 + c4] = *(const float4*)&Wv[(size_t)(kc+kk)*DD + c4];
        }
        __syncthreads();
        #pragma unroll
        for (int kk = 0; kk < 32; kk++){
            float xv[4];
            float4 wv[3];
            #pragma unroll
            for (int r = 0; r < 4; r++) xv[r] = xs[tr*4+r][kk];
            #pragma unroll
            for (int c = 0; c < 3; c++) wv[c] = *(float4*)&ws[kk][tc*12 + c*4];
            #pragma unroll
            for (int r = 0; r < 4; r++)
                #pragma unroll
                for (int c = 0; c < 3; c++){
                    acc[r][c].x = __builtin_fmaf(xv[r], wv[c].x, acc[r][c].x);
                    acc[r][c].y = __builtin_fmaf(xv[r], wv[c].y, acc[r][c].y);
                    acc[r][c].z = __builtin_fmaf(xv[r], wv[c].z, acc[r][c].z);
                    acc[r][c].w = __builtin_fmaf(xv[r], wv[c].w, acc[r][c].w);
                }
        }
    }
    // epilogue: bias + split write.  Each float4 group of 4 cols lies in one matrix.
    #pragma unroll
    for (int c = 0; c < 3; c++){
        int col = tc*12 + c*4;
        int sel = col >> 6;
        int d = col & 63;
        const float* bias = (sel==0) ? bq : (sel==1) ? bk : bv;
        float* dst = (sel==0) ? q : (sel==1) ? k : v;
        float4 b4 = *(const float4*)&bias[d];
        #pragma unroll
        for (int r = 0; r < 4; r++){
            size_t grow = (size_t)(row0 + tr*4 + r);
            float4 o;
            o.x = acc[r][c].x + b4.x;
            o.y = acc[r][c].y + b4.y;
            o.z = acc[r][c].z + b4.z;
            o.w = acc[r][c].w + b4.w;
            *(float4*)&dst[grow*DD + d] = o;
        }
    }
}

// K2: kp = exp(k @ w^T - 0.5||k||^2) / 16.  64 rows/block, m chunked by 64.
// Also accumulates ksum[b,m] = sum_t kp[b,t,m] via LDS reduce + 1 global atomic/elem.
__global__ __launch_bounds__(256) void kp_kernel(
    const float* __restrict__ k, const float* __restrict__ w,
    float* __restrict__ kp, float* __restrict__ ksum)
{
    __shared__ float ks_[64][68];
    __shared__ float ws_[64][68];
    __shared__ float xd_s[64];
    __shared__ float ksum_s[256];
    const int tid = threadIdx.x;
    const int row0 = blockIdx.x * 64;
    const int b = row0 >> 12;      // / 4096
    const int tr = tid >> 4, tc = tid & 15;

    #pragma unroll
    for (int i = 0; i < 4; i++){
        int l = tid + i*256;
        int r = l >> 4, c4 = (l & 15) << 2;
        *(float4*)&ks_[r][c4] = *(const float4*)&k[(size_t)(row0+r)*DD + c4];
    }
    ksum_s[tid] = 0.f;
    __syncthreads();
    {   // row norms: 4 threads/row, 16 d each, shfl reduce
        int rowx = tid >> 2, sub = tid & 3;
        float s = 0.f;
        #pragma unroll
        for (int j = 0; j < 4; j++){
            float4 kv = *(float4*)&ks_[rowx][sub*16 + j*4];
            s += kv.x*kv.x + kv.y*kv.y + kv.z*kv.z + kv.w*kv.w;
        }
        s += __shfl_xor(s, 1);
        s += __shfl_xor(s, 2);
        if (sub == 0) xd_s[rowx] = 0.5f * s;
    }

    for (int mc = 0; mc < 4; mc++){
        __syncthreads();
        #pragma unroll
        for (int i = 0; i < 4; i++){
            int l = tid + i*256;
            int r = l >> 4, c4 = (l & 15) << 2;
            *(float4*)&ws_[r][c4] = *(const float4*)&w[(size_t)(mc*64 + r)*DD + c4];
        }
        __syncthreads();
        float acc[4][4];
        #pragma unroll
        for (int r = 0; r < 4; r++)
            #pragma unroll
            for (int c = 0; c < 4; c++) acc[r][c] = 0.f;
        #pragma unroll
        for (int d4 = 0; d4 < 16; d4++){
            float4 qv[4], wv[4];
            #pragma unroll
            for (int r = 0; r < 4; r++) qv[r] = *(float4*)&ks_[tr*4+r][d4*4];
            #pragma unroll
            for (int c = 0; c < 4; c++) wv[c] = *(float4*)&ws_[tc + 16*c][d4*4];
            #pragma unroll
            for (int r = 0; r < 4; r++)
                #pragma unroll
                for (int c = 0; c < 4; c++) fma4(acc[r][c], qv[r], wv[c]);
        }
        float colsum[4] = {0.f, 0.f, 0.f, 0.f};
        #pragma unroll
        for (int r = 0; r < 4; r++){
            float xd = xd_s[tr*4+r];
            #pragma unroll
            for (int c = 0; c < 4; c++){
                float val = expf(acc[r][c] - xd) * 0.0625f;
                colsum[c] += val;
                kp[(size_t)(row0 + tr*4 + r)*MM + mc*64 + tc + 16*c] = val;
            }
        }
        #pragma unroll
        for (int c = 0; c < 4; c++)
            atomicAdd(&ksum_s[mc*64 + tc + 16*c], colsum[c]);
    }
    __syncthreads();
    unsafeAtomicAdd(&ksum[b*MM + tid], ksum_s[tid]);
}

// K3: kptv[b,n,m] += v^T @ kp.  Grid (TSPLIT, 4 m-chunks, 16 batches).
// Each block owns a [64 D x 64 M] output sub-tile over a T-slab of TT/TSPLIT rows.
// 16 acc/thread -> no spill; fp32 atomics into zeroed d_out region.
__global__ __launch_bounds__(256) void kptv_kernel(
    const float* __restrict__ v, const float* __restrict__ kp,
    float* __restrict__ out_kptv)
{
    __shared__ float vs[32][68];
    __shared__ float kps[32][68];
    const int tid = threadIdx.x;
    const int b  = blockIdx.z;
    const int mc = blockIdx.y;                 // m chunk of 64
    const int t0 = blockIdx.x * (TT/TSPLIT);   // 256-row T slab
    const int tn = tid >> 4, tm = tid & 15;    // tn: 4-wide d group, tm: 4-wide m group

    float acc[4][4];
    #pragma unroll
    for (int r = 0; r < 4; r++)
        #pragma unroll
        for (int c = 0; c < 4; c++) acc[r][c] = 0.f;

    for (int tt = 0; tt < TT/TSPLIT; tt += 32){
        __syncthreads();
        #pragma unroll
        for (int i = 0; i < 2; i++){
            int l = tid + i*256;
            int r = l >> 4, c4 = (l & 15) << 2;
            *(float4*)&vs[r][c4]  = *(const float4*)&v [(size_t)(b*TT + t0 + tt + r)*DD + c4];
            *(float4*)&kps[r][c4] = *(const float4*)&kp[(size_t)(b*TT + t0 + tt + r)*MM + mc*64 + c4];
        }
        __syncthreads();
        #pragma unroll
        for (int t = 0; t < 32; t++){
            float vv[4], kv[4];
            *(float4*)vv = *(float4*)&vs[t][tn*4];    // broadcast within 16-lane groups
            *(float4*)kv = *(float4*)&kps[t][tm*4];
            #pragma unroll
            for (int r = 0; r < 4; r++)
                #pragma unroll
                for (int c = 0; c < 4; c++)
                    acc[r][c] = __builtin_fmaf(vv[r], kv[c], acc[r][c]);
        }
    }
    #pragma unroll
    for (int r = 0; r < 4; r++)
        #pragma unroll
        for (int c = 0; c < 4; c++)
            unsafeAtomicAdd(&out_kptv[(size_t)b*DD*MM + (size_t)(tn*4+r)*MM + mc*64 + tm*4 + c],
                            acc[r][c]);
}

// K4: qp = prm_exp(q) recomputed on the fly; attn = (qp @ kptv^T) / (qp . ksum).
__global__ __launch_bounds__(256) void attn_kernel(
    const float* __restrict__ q, const float* __restrict__ w,
    const float* __restrict__ kptv, const float* __restrict__ ksum,
    float* __restrict__ out)
{
    __shared__ float qs[64][68];
    __shared__ float wqp[64][68];   // holds w chunk during GEMM1, qp tile during GEMM2
    __shared__ float kvs[64][68];   // kptv chunk [n][m-chunk]
    __shared__ float ksum_s[256];
    __shared__ float xd_s[64];
    const int tid = threadIdx.x;
    const int row0 = blockIdx.x * 64;
    const int b = row0 >> 12;       // /4096
    const int tr = tid >> 4, tc = tid & 15;

    #pragma unroll
    for (int i = 0; i < 4; i++){
        int l = tid + i*256;
        int r = l >> 4, c4 = (l & 15) << 2;
        *(float4*)&qs[r][c4] = *(const float4*)&q[(size_t)(row0 + r)*DD + c4];
    }
    ksum_s[tid] = ksum[b*MM + tid];
    __syncthreads();
    {
        int rowx = tid >> 2, sub = tid & 3;
        float s = 0.f;
        #pragma unroll
        for (int j = 0; j < 4; j++){
            float4 qv = *(float4*)&qs[rowx][sub*16 + j*4];
            s += qv.x*qv.x + qv.y*qv.y + qv.z*qv.z + qv.w*qv.w;
        }
        s += __shfl_xor(s, 1);
        s += __shfl_xor(s, 2);
        if (sub == 0) xd_s[rowx] = 0.5f * s;
    }

    float acc2[4][4];
    float dn[4];
    #pragma unroll
    for (int r = 0; r < 4; r++){
        dn[r] = 0.f;
        #pragma unroll
        for (int c = 0; c < 4; c++) acc2[r][c] = 0.f;
    }

    for (int mc = 0; mc < 4; mc++){
        __syncthreads();   // prev GEMM2 readers done; xd_s visible on first iter
        #pragma unroll
        for (int i = 0; i < 4; i++){
            int l = tid + i*256;
            int r = l >> 4, c4 = (l & 15) << 2;
            *(float4*)&wqp[r][c4] = *(const float4*)&w[(size_t)(mc*64 + r)*DD + c4];
            *(float4*)&kvs[r][c4] = *(const float4*)&kptv[(size_t)b*DD*MM + r*MM + mc*64 + c4];
        }
        __syncthreads();
        // GEMM1: wtx for m-chunk
        float acc1[4][4];
        #pragma unroll
        for (int r = 0; r < 4; r++)
            #pragma unroll
            for (int c = 0; c < 4; c++) acc1[r][c] = 0.f;
        #pragma unroll
        for (int d4 = 0; d4 < 16; d4++){
            float4 qv[4], wv[4];
            #pragma unroll
            for (int r = 0; r < 4; r++) qv[r] = *(float4*)&qs[tr*4+r][d4*4];
            #pragma unroll
            for (int c = 0; c < 4; c++) wv[c] = *(float4*)&wqp[tc + 16*c][d4*4];
            #pragma unroll
            for (int r = 0; r < 4; r++)
                #pragma unroll
                for (int c = 0; c < 4; c++) fma4(acc1[r][c], qv[r], wv[c]);
        }
        // exp + Dn partials
        float qp_[4][4];
        #pragma unroll
        for (int r = 0; r < 4; r++){
            float xd = xd_s[tr*4+r];
            #pragma unroll
            for (int c = 0; c < 4; c++){
                float val = expf(acc1[r][c] - xd) * 0.0625f;
                qp_[r][c] = val;
                dn[r] = __builtin_fmaf(val, ksum_s[mc*64 + tc + 16*c], dn[r]);
            }
        }
        __syncthreads();   // everyone done reading w chunk
        #pragma unroll
        for (int r = 0; r < 4; r++)
            #pragma unroll
            for (int c = 0; c < 4; c++)
                wqp[tr*4+r][tc + 16*c] = qp_[r][c];
        __syncthreads();
        // GEMM2: acc2 += qp_tile @ kptv_chunk^T
        #pragma unroll
        for (int m4 = 0; m4 < 16; m4++){
            float4 qv[4], kv[4];
            #pragma unroll
            for (int r = 0; r < 4; r++) qv[r] = *(float4*)&wqp[tr*4+r][m4*4];
            #pragma unroll
            for (int c = 0; c < 4; c++) kv[c] = *(float4*)&kvs[tc + 16*c][m4*4];
            #pragma unroll
            for (int r = 0; r < 4; r++)
                #pragma unroll
                for (int c = 0; c < 4; c++) fma4(acc2[r][c], qv[r], kv[c]);
        }
    }
    #pragma unroll
    for (int r = 0; r < 4; r++){
        dn[r] += __shfl_xor(dn[r], 1);
        dn[r] += __shfl_xor(dn[r], 2);
        dn[r] += __shfl_xor(dn[r], 4);
        dn[r] += __shfl_xor(dn[r], 8);
    }
    #pragma unroll
    for (int r = 0; r < 4; r++){
        float inv = 1.0f / dn[r];
        #pragma unroll
        for (int c = 0; c < 4; c++)
            out[(size_t)(row0 + tr*4 + r)*DD + tc + 16*c] = acc2[r][c] * inv;
    }
}

extern "C" void kernel_launch(void* const* d_in, const int* in_sizes, int n_in,
                              void* d_out, int out_size, void* d_ws, size_t ws_size,
                              hipStream_t stream) {
    const float* x  = (const float*)d_in[0];
    const float* Wq = (const float*)d_in[1];
    const float* bq = (const float*)d_in[2];
    const float* Wk = (const float*)d_in[3];
    const float* bk = (const float*)d_in[4];
    const float* Wv = (const float*)d_in[5];
    const float* bv = (const float*)d_in[6];
    const float* w  = (const float*)d_in[7];

    float* out_attn = (float*)d_out;
    float* out_kptv = out_attn + (size_t)BB*TT*DD;

    float* q    = (float*)d_ws;                 // BT*64
    float* k    = q + (size_t)BT*DD;            // BT*64
    float* v    = k + (size_t)BT*DD;            // BT*64
    float* kp   = v + (size_t)BT*DD;            // BT*256
    float* ksum = kp + (size_t)BT*MM;           // B*256
    // total ws: ~112 MB

    hipMemsetAsync(out_kptv, 0, (size_t)BB*DD*MM*sizeof(float), stream);
    hipMemsetAsync(ksum, 0, (size_t)BB*MM*sizeof(float), stream);

    qkv_kernel<<<BT/64, 256, 0, stream>>>(x, Wq, bq, Wk, bk, Wv, bv, q, k, v);
    kp_kernel<<<BT/64, 256, 0, stream>>>(k, w, kp, ksum);
    kptv_kernel<<<dim3(TSPLIT, 4, BB), 256, 0, stream>>>(v, kp, out_kptv);
    attn_kernel<<<BT/64, 256, 0, stream>>>(q, w, out_kptv, ksum, out_attn);
}

// Round 7
// 546.222 us; speedup vs baseline: 2.0636x; 1.2447x over previous
//
#include <hip/hip_runtime.h>
#include <math.h>

#define BB 16
#define TT 4096
#define HH 768
#define DD 64
#define MM 256
#define BT (BB*TT)
#define TSPLIT 16

typedef __attribute__((ext_vector_type(8))) short bf16x8;
typedef __attribute__((ext_vector_type(4))) float f32x4;

union frag_u { bf16x8 v; ushort4 h[2]; };

// 8-byte-granular LDS accessors: rows of the bf16 tiles are 80 B (not 16-mult),
// so 16B ds ops would be misaligned on odd rows.
__device__ __forceinline__ bf16x8 ld_frag(const unsigned short* p){
    frag_u u;
    u.h[0] = *(const ushort4*)p;
    u.h[1] = *(const ushort4*)(p + 4);
    return u.v;
}
__device__ __forceinline__ void st8(unsigned short* p, bf16x8 t){
    frag_u u; u.v = t;
    *(ushort4*)p       = u.h[0];
    *(ushort4*)(p + 4) = u.h[1];
}

__device__ __forceinline__ void fma4(float& acc, float4 a, float4 b){
    acc = __builtin_fmaf(a.x, b.x, acc);
    acc = __builtin_fmaf(a.y, b.y, acc);
    acc = __builtin_fmaf(a.z, b.z, acc);
    acc = __builtin_fmaf(a.w, b.w, acc);
}

__device__ __forceinline__ unsigned short f2bf_rn(float f){
    unsigned u = __builtin_bit_cast(unsigned, f);
    unsigned r = u + 0x7FFFu + ((u >> 16) & 1u);
    return (unsigned short)(r >> 16);
}
__device__ __forceinline__ float bf2f(unsigned short h){
    unsigned u = ((unsigned)h) << 16;
    return __builtin_bit_cast(float, u);
}

// K0: split Wq|Wk|Wv into bf16 hi/lo, transposed + K-tiled: layout [k/32][n][k%32].
// Also concatenates biases into bias_all[192].
__global__ __launch_bounds__(256) void wcvt_kernel(
    const float* __restrict__ Wq, const float* __restrict__ Wk, const float* __restrict__ Wv,
    const float* __restrict__ bq, const float* __restrict__ bk, const float* __restrict__ bv,
    unsigned short* __restrict__ wt_hi, unsigned short* __restrict__ wt_lo,
    float* __restrict__ bias_all)
{
    int idx = blockIdx.x * 256 + threadIdx.x;      // 0..147455
    int n = idx / 768, kk = idx - n*768;
    int sel = n >> 6, d = n & 63;
    const float* W = (sel==0) ? Wq : (sel==1) ? Wk : Wv;
    float f = W[kk*DD + d];
    unsigned short hi = f2bf_rn(f);
    float lo = f - bf2f(hi);
    unsigned short lov = f2bf_rn(lo);
    size_t off = ((size_t)(kk >> 5)*192 + n)*32 + (kk & 31);
    wt_hi[off] = hi;
    wt_lo[off] = lov;
    if (idx < 192)
        bias_all[idx] = (idx < 64) ? bq[idx] : (idx < 128) ? bk[idx-64] : bv[idx-128];
}

// K1: q/k/v = x @ [Wq|Wk|Wv] + bias via split-bf16 MFMA (hh + hl + lh terms).
// BM=128, BN=192 (full N), BK=32, 8 waves (4M x 2N), each wave 32 rows x 96 cols.
__global__ __launch_bounds__(512) void qkv_mfma_kernel(
    const float* __restrict__ x,
    const unsigned short* __restrict__ wt_hi, const unsigned short* __restrict__ wt_lo,
    const float* __restrict__ bias_all,
    float* __restrict__ q, float* __restrict__ k, float* __restrict__ v)
{
    __shared__ unsigned short Ah[128][40];   // 80B row stride: 2-way bank alias (free);
    __shared__ unsigned short Al[128][40];   // all LDS access in 8B units (alignment!)
    __shared__ unsigned short Bh[192][40];
    __shared__ unsigned short Bl[192][40];
    const int tid  = threadIdx.x;
    const int lane = tid & 63;
    const int wid  = tid >> 6;
    const int wm   = wid & 3;       // wave M index (rows wm*32..+31)
    const int wn   = wid >> 2;      // wave N index (cols wn*96..+95)
    const int row0 = blockIdx.x * 128;

    f32x4 acc[2][6] = {};

    for (int kc = 0; kc < HH; kc += 32){
        __syncthreads();
        // ---- stage A: x[128][32] fp32 -> hi/lo bf16 (8B LDS stores, aligned) ----
        #pragma unroll
        for (int i = 0; i < 2; i++){
            int l = tid + i*512;              // 0..1023
            int r = l >> 3, c4 = (l & 7) << 2;
            float4 xv = *(const float4*)&x[(size_t)(row0 + r)*HH + kc + c4];
            ushort4 hv, lv;
            hv.x = f2bf_rn(xv.x); lv.x = f2bf_rn(xv.x - bf2f(hv.x));
            hv.y = f2bf_rn(xv.y); lv.y = f2bf_rn(xv.y - bf2f(hv.y));
            hv.z = f2bf_rn(xv.z); lv.z = f2bf_rn(xv.z - bf2f(hv.z));
            hv.w = f2bf_rn(xv.w); lv.w = f2bf_rn(xv.w - bf2f(hv.w));
            *(ushort4*)&Ah[r][c4] = hv;
            *(ushort4*)&Al[r][c4] = lv;
        }
        // ---- stage B: wt tile [192][32] bf16 hi|lo = 1536 16B-chunks.
        //      (round-6 fix: 768 is NOT pow2 — use explicit l<768 split, not &767) ----
        {
            const unsigned short* srch = wt_hi + (size_t)(kc >> 5)*192*32;
            const unsigned short* srcl = wt_lo + (size_t)(kc >> 5)*192*32;
            #pragma unroll
            for (int i = 0; i < 3; i++){
                int l = tid + i*512;          // 0..1535
                if (l < 768){
                    int r = l >> 2, c8 = (l & 3) << 3;
                    bf16x8 t = *(const bf16x8*)(srch + (size_t)l*8);
                    st8(&Bh[r][c8], t);
                } else {
                    int l2 = l - 768;         // 0..767
                    int r = l2 >> 2, c8 = (l2 & 3) << 3;
                    bf16x8 t = *(const bf16x8*)(srcl + (size_t)l2*8);
                    st8(&Bl[r][c8], t);
                }
            }
        }
        __syncthreads();
        // ---- MFMA: acc += Ah*Bh + Ah*Bl + Al*Bh ----
        bf16x8 ah[2], al[2];
        #pragma unroll
        for (int mi = 0; mi < 2; mi++){
            int ar = wm*32 + mi*16 + (lane & 15);
            int ak = (lane >> 4) << 3;
            ah[mi] = ld_frag(&Ah[ar][ak]);
            al[mi] = ld_frag(&Al[ar][ak]);
        }
        #pragma unroll
        for (int ni = 0; ni < 6; ni++){
            int bc = wn*96 + ni*16 + (lane & 15);
            int bk_ = (lane >> 4) << 3;
            bf16x8 bh = ld_frag(&Bh[bc][bk_]);
            bf16x8 bl = ld_frag(&Bl[bc][bk_]);
            #pragma unroll
            for (int mi = 0; mi < 2; mi++){
                acc[mi][ni] = __builtin_amdgcn_mfma_f32_16x16x32_bf16(ah[mi], bh, acc[mi][ni], 0, 0, 0);
                acc[mi][ni] = __builtin_amdgcn_mfma_f32_16x16x32_bf16(ah[mi], bl, acc[mi][ni], 0, 0, 0);
                acc[mi][ni] = __builtin_amdgcn_mfma_f32_16x16x32_bf16(al[mi], bh, acc[mi][ni], 0, 0, 0);
            }
        }
    }
    // ---- epilogue: bias + split store (C layout: col=lane&15, row=(lane>>4)*4+j) ----
    #pragma unroll
    for (int ni = 0; ni < 6; ni++){
        int col = wn*96 + ni*16 + (lane & 15);
        int sel = col >> 6, d = col & 63;
        float bias = bias_all[col];
        float* dst = (sel==0) ? q : (sel==1) ? k : v;
        #pragma unroll
        for (int mi = 0; mi < 2; mi++){
            int rbase = row0 + wm*32 + mi*16 + ((lane >> 4) << 2);
            #pragma unroll
            for (int j = 0; j < 4; j++){
                dst[(size_t)(rbase + j)*DD + d] = acc[mi][ni][j] + bias;
            }
        }
    }
}

// K2: kp = exp(k @ w^T - 0.5||k||^2) / 16.  64 rows/block, m chunked by 64.
// Also accumulates ksum[b,m] = sum_t kp[b,t,m] via LDS reduce + 1 global atomic/elem.
__global__ __launch_bounds__(256) void kp_kernel(
    const float* __restrict__ k, const float* __restrict__ w,
    float* __restrict__ kp, float* __restrict__ ksum)
{
    __shared__ float ks_[64][68];
    __shared__ float ws_[64][68];
    __shared__ float xd_s[64];
    __shared__ float ksum_s[256];
    const int tid = threadIdx.x;
    const int row0 = blockIdx.x * 64;
    const int b = row0 >> 12;      // / 4096
    const int tr = tid >> 4, tc = tid & 15;

    #pragma unroll
    for (int i = 0; i < 4; i++){
        int l = tid + i*256;
        int r = l >> 4, c4 = (l & 15) << 2;
        *(float4*)&ks_[r][c4] = *(const float4*)&k[(size_t)(row0+r)*DD + c4];
    }
    ksum_s[tid] = 0.f;
    __syncthreads();
    {   // row norms: 4 threads/row, 16 d each, shfl reduce
        int rowx = tid >> 2, sub = tid & 3;
        float s = 0.f;
        #pragma unroll
        for (int j = 0; j < 4; j++){
            float4 kv = *(float4*)&ks_[rowx][sub*16 + j*4];
            s += kv.x*kv.x + kv.y*kv.y + kv.z*kv.z + kv.w*kv.w;
        }
        s += __shfl_xor(s, 1);
        s += __shfl_xor(s, 2);
        if (sub == 0) xd_s[rowx] = 0.5f * s;
    }

    for (int mc = 0; mc < 4; mc++){
        __syncthreads();
        #pragma unroll
        for (int i = 0; i < 4; i++){
            int l = tid + i*256;
            int r = l >> 4, c4 = (l & 15) << 2;
            *(float4*)&ws_[r][c4] = *(const float4*)&w[(size_t)(mc*64 + r)*DD + c4];
        }
        __syncthreads();
        float acc[4][4];
        #pragma unroll
        for (int r = 0; r < 4; r++)
            #pragma unroll
            for (int c = 0; c < 4; c++) acc[r][c] = 0.f;
        #pragma unroll
        for (int d4 = 0; d4 < 16; d4++){
            float4 qv[4], wv[4];
            #pragma unroll
            for (int r = 0; r < 4; r++) qv[r] = *(float4*)&ks_[tr*4+r][d4*4];
            #pragma unroll
            for (int c = 0; c < 4; c++) wv[c] = *(float4*)&ws_[tc + 16*c][d4*4];
            #pragma unroll
            for (int r = 0; r < 4; r++)
                #pragma unroll
                for (int c = 0; c < 4; c++) fma4(acc[r][c], qv[r], wv[c]);
        }
        float colsum[4] = {0.f, 0.f, 0.f, 0.f};
        #pragma unroll
        for (int r = 0; r < 4; r++){
            float xd = xd_s[tr*4+r];
            #pragma unroll
            for (int c = 0; c < 4; c++){
                float val = expf(acc[r][c] - xd) * 0.0625f;
                colsum[c] += val;
                kp[(size_t)(row0 + tr*4 + r)*MM + mc*64 + tc + 16*c] = val;
            }
        }
        #pragma unroll
        for (int c = 0; c < 4; c++)
            atomicAdd(&ksum_s[mc*64 + tc + 16*c], colsum[c]);
    }
    __syncthreads();
    unsafeAtomicAdd(&ksum[b*MM + tid], ksum_s[tid]);
}

// K3: kptv[b,n,m] += v^T @ kp.  Grid (TSPLIT, 4 m-chunks, 16 batches).
__global__ __launch_bounds__(256) void kptv_kernel(
    const float* __restrict__ v, const float* __restrict__ kp,
    float* __restrict__ out_kptv)
{
    __shared__ float vs[32][68];
    __shared__ float kps[32][68];
    const int tid = threadIdx.x;
    const int b  = blockIdx.z;
    const int mc = blockIdx.y;                 // m chunk of 64
    const int t0 = blockIdx.x * (TT/TSPLIT);   // 256-row T slab
    const int tn = tid >> 4, tm = tid & 15;

    float acc[4][4];
    #pragma unroll
    for (int r = 0; r < 4; r++)
        #pragma unroll
        for (int c = 0; c < 4; c++) acc[r][c] = 0.f;

    for (int tt = 0; tt < TT/TSPLIT; tt += 32){
        __syncthreads();
        #pragma unroll
        for (int i = 0; i < 2; i++){
            int l = tid + i*256;
            int r = l >> 4, c4 = (l & 15) << 2;
            *(float4*)&vs[r][c4]  = *(const float4*)&v [(size_t)(b*TT + t0 + tt + r)*DD + c4];
            *(float4*)&kps[r][c4] = *(const float4*)&kp[(size_t)(b*TT + t0 + tt + r)*MM + mc*64 + c4];
        }
        __syncthreads();
        #pragma unroll
        for (int t = 0; t < 32; t++){
            float vv[4], kv[4];
            *(float4*)vv = *(float4*)&vs[t][tn*4];
            *(float4*)kv = *(float4*)&kps[t][tm*4];
            #pragma unroll
            for (int r = 0; r < 4; r++)
                #pragma unroll
                for (int c = 0; c < 4; c++)
                    acc[r][c] = __builtin_fmaf(vv[r], kv[c], acc[r][c]);
        }
    }
    #pragma unroll
    for (int r = 0; r < 4; r++)
        #pragma unroll
        for (int c = 0; c < 4; c++)
            unsafeAtomicAdd(&out_kptv[(size_t)b*DD*MM + (size_t)(tn*4+r)*MM + mc*64 + tm*4 + c],
                            acc[r][c]);
}

// K4: qp = prm_exp(q) recomputed on the fly; attn = (qp @ kptv^T) / (qp . ksum).
__global__ __launch_bounds__(256) void attn_kernel(
    const float* __restrict__ q, const float* __restrict__ w,
    const float* __restrict__ kptv, const float* __restrict__ ksum,
    float* __restrict__ out)
{
    __shared__ float qs[64][68];
    __shared__ float wqp[64][68];
    __shared__ float kvs[64][68];
    __shared__ float ksum_s[256];
    __shared__ float xd_s[64];
    const int tid = threadIdx.x;
    const int row0 = blockIdx.x * 64;
    const int b = row0 >> 12;
    const int tr = tid >> 4, tc = tid & 15;

    #pragma unroll
    for (int i = 0; i < 4; i++){
        int l = tid + i*256;
        int r = l >> 4, c4 = (l & 15) << 2;
        *(float4*)&qs[r][c4] = *(const float4*)&q[(size_t)(row0 + r)*DD + c4];
    }
    ksum_s[tid] = ksum[b*MM + tid];
    __syncthreads();
    {
        int rowx = tid >> 2, sub = tid & 3;
        float s = 0.f;
        #pragma unroll
        for (int j = 0; j < 4; j++){
            float4 qv = *(float4*)&qs[rowx][sub*16 + j*4];
            s += qv.x*qv.x + qv.y*qv.y + qv.z*qv.z + qv.w*qv.w;
        }
        s += __shfl_xor(s, 1);
        s += __shfl_xor(s, 2);
        if (sub == 0) xd_s[rowx] = 0.5f * s;
    }

    float acc2[4][4];
    float dn[4];
    #pragma unroll
    for (int r = 0; r < 4; r++){
        dn[r] = 0.f;
        #pragma unroll
        for (int c = 0; c < 4; c++) acc2[r][c] = 0.f;
    }

    for (int mc = 0; mc < 4; mc++){
        __syncthreads();
        #pragma unroll
        for (int i = 0; i < 4; i++){
            int l = tid + i*256;
            int r = l >> 4, c4 = (l & 15) << 2;
            *(float4*)&wqp[r][c4] = *(const float4*)&w[(size_t)(mc*64 + r)*DD + c4];
            *(float4*)&kvs[r][c4] = *(const float4*)&kptv[(size_t)b*DD*MM + r*MM + mc*64 + c4];
        }
        __syncthreads();
        float acc1[4][4];
        #pragma unroll
        for (int r = 0; r < 4; r++)
            #pragma unroll
            for (int c = 0; c < 4; c++) acc1[r][c] = 0.f;
        #pragma unroll
        for (int d4 = 0; d4 < 16; d4++){
            float4 qv[4], wv[4];
            #pragma unroll
            for (int r = 0; r < 4; r++) qv[r] = *(float4*)&qs[tr*4+r][d4*4];
            #pragma unroll
            for (int c = 0; c < 4; c++) wv[c] = *(float4*)&wqp[tc + 16*c][d4*4];
            #pragma unroll
            for (int r = 0; r < 4; r++)
                #pragma unroll
                for (int c = 0; c < 4; c++) fma4(acc1[r][c], qv[r], wv[c]);
        }
        float qp_[4][4];
        #pragma unroll
        for (int r = 0; r < 4; r++){
            float xd = xd_s[tr*4+r];
            #pragma unroll
            for (int c = 0; c < 4; c++){
                float val = expf(acc1[r][c] - xd) * 0.0625f;
                qp_[r][c] = val;
                dn[r] = __builtin_fmaf(val, ksum_s[mc*64 + tc + 16*c], dn[r]);
            }
        }
        __syncthreads();
        #pragma unroll
        for (int r = 0; r < 4; r++)
            #pragma unroll
            for (int c = 0; c < 4; c++)
                wqp[tr*4+r][tc + 16*c] = qp_[r][c];
        __syncthreads();
        #pragma unroll
        for (int m4 = 0; m4 < 16; m4++){
            float4 qv[4], kv[4];
            #pragma unroll
            for (int r = 0; r < 4; r++) qv[r] = *(float4*)&wqp[tr*4+r][m4*4];
            #pragma unroll
            for (int c = 0; c < 4; c++) kv[c] = *(float4*)&kvs[tc + 16*c][m4*4];
            #pragma unroll
            for (int r = 0; r < 4; r++)
                #pragma unroll
                for (int c = 0; c < 4; c++) fma4(acc2[r][c], qv[r], kv[c]);
        }
    }
    #pragma unroll
    for (int r = 0; r < 4; r++){
        dn[r] += __shfl_xor(dn[r], 1);
        dn[r] += __shfl_xor(dn[r], 2);
        dn[r] += __shfl_xor(dn[r], 4);
        dn[r] += __shfl_xor(dn[r], 8);
    }
    #pragma unroll
    for (int r = 0; r < 4; r++){
        float inv = 1.0f / dn[r];
        #pragma unroll
        for (int c = 0; c < 4; c++)
            out[(size_t)(row0 + tr*4 + r)*DD + tc + 16*c] = acc2[r][c] * inv;
    }
}

extern "C" void kernel_launch(void* const* d_in, const int* in_sizes, int n_in,
                              void* d_out, int out_size, void* d_ws, size_t ws_size,
                              hipStream_t stream) {
    const float* x  = (const float*)d_in[0];
    const float* Wq = (const float*)d_in[1];
    const float* bq = (const float*)d_in[2];
    const float* Wk = (const float*)d_in[3];
    const float* bk = (const float*)d_in[4];
    const float* Wv = (const float*)d_in[5];
    const float* bv = (const float*)d_in[6];
    const float* w  = (const float*)d_in[7];

    float* out_attn = (float*)d_out;
    float* out_kptv = out_attn + (size_t)BB*TT*DD;

    float* q    = (float*)d_ws;                 // BT*64
    float* k    = q + (size_t)BT*DD;            // BT*64
    float* v    = k + (size_t)BT*DD;            // BT*64
    float* kp   = v + (size_t)BT*DD;            // BT*256
    float* ksum = kp + (size_t)BT*MM;           // B*256
    unsigned short* wt_hi = (unsigned short*)(ksum + BB*MM);   // 768*192 bf16
    unsigned short* wt_lo = wt_hi + (size_t)HH*192;
    float* bias_all = (float*)(wt_lo + (size_t)HH*192);        // 192 floats

    hipMemsetAsync(out_kptv, 0, (size_t)BB*DD*MM*sizeof(float), stream);
    hipMemsetAsync(ksum, 0, (size_t)BB*MM*sizeof(float), stream);

    wcvt_kernel<<<(HH*192)/256, 256, 0, stream>>>(Wq, Wk, Wv, bq, bk, bv, wt_hi, wt_lo, bias_all);
    qkv_mfma_kernel<<<BT/128, 512, 0, stream>>>(x, wt_hi, wt_lo, bias_all, q, k, v);
    kp_kernel<<<BT/64, 256, 0, stream>>>(k, w, kp, ksum);
    kptv_kernel<<<dim3(TSPLIT, 4, BB), 256, 0, stream>>>(v, kp, out_kptv);
    attn_kernel<<<BT/64, 256, 0, stream>>>(q, w, out_kptv, ksum, out_attn);
}